// Round 1
// baseline (79.924 us; speedup 1.0000x reference)
//
#include <hip/hip_runtime.h>

#define HID 256
#define LK  2048
#define LQ  64
#define BSZ 8
#define M   16
#define NKEY (BSZ * M)   // 128

// ---------------------------------------------------------------------------
// Kernel A: partial column sums of key (and full column sums of query).
// Blocks [0, NKEY*split): key chunk sums -> partial[bid][256]
// Blocks [NKEY*split, NKEY*split+BSZ): query sums -> qsum[b][256]
// ---------------------------------------------------------------------------
__global__ void colsum_kernel(const float* __restrict__ query,
                              const float* __restrict__ key,
                              float* __restrict__ partial,
                              float* __restrict__ qsum,
                              int split) {
    const int bid  = blockIdx.x;
    const int t    = threadIdx.x;
    const int wave = t >> 6;
    const int lane = t & 63;
    const int nK   = NKEY * split;

    const float* base;
    float* dst;
    int rows;
    if (bid < nK) {
        const int n = bid / split, chunk = bid % split;
        rows = LK / split;
        base = key + (size_t)n * LK * HID + (size_t)chunk * rows * HID;
        dst  = partial + (size_t)bid * HID;
    } else {
        const int b = bid - nK;
        rows = LQ;
        base = query + (size_t)b * LQ * HID;
        dst  = qsum + (size_t)b * HID;
    }

    float4 acc = make_float4(0.f, 0.f, 0.f, 0.f);
    // wave w handles rows w, w+4, w+8, ... ; lane covers 4 consecutive columns
    for (int r = wave; r < rows; r += 4) {
        float4 v = ((const float4*)(base + (size_t)r * HID))[lane];
        acc.x += v.x; acc.y += v.y; acc.z += v.z; acc.w += v.w;
    }

    __shared__ float lds[4][HID];
    ((float4*)lds[wave])[lane] = acc;
    __syncthreads();
    float s = lds[0][t] + lds[1][t] + lds[2][t] + lds[3][t];
    dst[t] = s;
}

// ---------------------------------------------------------------------------
// Kernel B: reduce the split partials and apply the linear projection.
// Blocks [0, NKEY): ksv[n][o] = ksum[n][:].w_k[o][:] + LK*b_k[o]
// Blocks [NKEY, NKEY+BSZ): qsv[b][o] = qsum[b][:].w_q[o][:] + LQ*b_q[o]
// ---------------------------------------------------------------------------
__global__ void project_kernel(const float* __restrict__ partial,
                               const float* __restrict__ qsum,
                               const float* __restrict__ w_q,
                               const float* __restrict__ b_q,
                               const float* __restrict__ w_k,
                               const float* __restrict__ b_k,
                               float* __restrict__ ksv,
                               float* __restrict__ qsv,
                               int split) {
    __shared__ float sred[HID];
    const int bid = blockIdx.x;
    const int t   = threadIdx.x;

    const float* W;
    const float* bias;
    float lfac;
    float* dst;
    if (bid < NKEY) {
        float s = 0.f;
        for (int c = 0; c < split; ++c)
            s += partial[((size_t)bid * split + c) * HID + t];
        sred[t] = s;
        W = w_k; bias = b_k; lfac = (float)LK; dst = ksv + (size_t)bid * HID;
    } else {
        const int b = bid - NKEY;
        sred[t] = qsum[(size_t)b * HID + t];
        W = w_q; bias = b_q; lfac = (float)LQ; dst = qsv + (size_t)b * HID;
    }
    __syncthreads();

    const float4* Wrow = (const float4*)(W + (size_t)t * HID);
    float acc = 0.f;
#pragma unroll 8
    for (int h4 = 0; h4 < HID / 4; ++h4) {
        float4 w = Wrow[h4];
        acc += w.x * sred[h4 * 4 + 0] + w.y * sred[h4 * 4 + 1]
             + w.z * sred[h4 * 4 + 2] + w.w * sred[h4 * 4 + 3];
    }
    dst[t] = acc + lfac * bias[t];
}

// ---------------------------------------------------------------------------
// Kernel C: attention[b][m] = qsv[b][:].ksv[b*M+m][:]; argmax over m -> idx[b]
// One block per b. First-max tie-break matches jnp.argmax (strict >).
// ---------------------------------------------------------------------------
__global__ void argmax_kernel(const float* __restrict__ ksv,
                              const float* __restrict__ qsv,
                              int* __restrict__ idx) {
    const int b    = blockIdx.x;
    const int t    = threadIdx.x;
    const int wave = t >> 6;
    const int lane = t & 63;

    __shared__ float att[M];
    __shared__ float wpart[4];

    const float q = qsv[(size_t)b * HID + t];
    for (int m = 0; m < M; ++m) {
        float v = q * ksv[((size_t)b * M + m) * HID + t];
        for (int off = 32; off; off >>= 1) v += __shfl_down(v, off);
        if (lane == 0) wpart[wave] = v;
        __syncthreads();
        if (t == 0) att[m] = wpart[0] + wpart[1] + wpart[2] + wpart[3];
        __syncthreads();
    }
    if (t == 0) {
        int best = 0;
        float bv = att[0];
        for (int m = 1; m < M; ++m)
            if (att[m] > bv) { bv = att[m]; best = m; }
        idx[b] = best;
    }
}

// ---------------------------------------------------------------------------
// Kernel D: out[b][k][h] = key[b*M + idx[b]][k][h]   (float4 copy)
// ---------------------------------------------------------------------------
__global__ void gather_kernel(const float* __restrict__ key,
                              const int* __restrict__ idx,
                              float* __restrict__ out) {
    const size_t per_b = (size_t)LK * HID / 4;  // float4s per batch item
    const size_t i = (size_t)blockIdx.x * blockDim.x + threadIdx.x;
    const int b = (int)(i / per_b);
    const size_t off = i % per_b;
    const int n = b * M + idx[b];
    ((float4*)out)[i] = ((const float4*)key)[(size_t)n * per_b + off];
}

extern "C" void kernel_launch(void* const* d_in, const int* in_sizes, int n_in,
                              void* d_out, int out_size, void* d_ws, size_t ws_size,
                              hipStream_t stream) {
    const float* query = (const float*)d_in[0];
    const float* key   = (const float*)d_in[1];
    const float* w_q   = (const float*)d_in[2];
    const float* b_q   = (const float*)d_in[3];
    const float* w_k   = (const float*)d_in[4];
    const float* b_k   = (const float*)d_in[5];
    float* out = (float*)d_out;

    // pick the largest split whose partial buffer fits in the workspace
    int split = 16;
    while (split > 1) {
        size_t need = sizeof(float) * ((size_t)NKEY * split * HID  // partial
                                       + (size_t)BSZ * HID         // qsum
                                       + (size_t)NKEY * HID        // ksv
                                       + (size_t)BSZ * HID)        // qsv
                      + sizeof(int) * BSZ;                         // idx
        if (need <= ws_size) break;
        split >>= 1;
    }

    float* ws = (float*)d_ws;
    size_t off = 0;
    float* partial = ws + off; off += (size_t)NKEY * split * HID;
    float* qsum    = ws + off; off += (size_t)BSZ * HID;
    float* ksv     = ws + off; off += (size_t)NKEY * HID;
    float* qsv     = ws + off; off += (size_t)BSZ * HID;
    int*   idx     = (int*)(ws + off);

    const int nColBlocks = NKEY * split + BSZ;
    hipLaunchKernelGGL(colsum_kernel, dim3(nColBlocks), dim3(256), 0, stream,
                       query, key, partial, qsum, split);

    hipLaunchKernelGGL(project_kernel, dim3(NKEY + BSZ), dim3(256), 0, stream,
                       partial, qsum, w_q, b_q, w_k, b_k, ksv, qsv, split);

    hipLaunchKernelGGL(argmax_kernel, dim3(BSZ), dim3(256), 0, stream,
                       ksv, qsv, idx);

    const int nGatherBlocks = (int)((size_t)BSZ * LK * HID / 4 / 256);  // 4096
    hipLaunchKernelGGL(gather_kernel, dim3(nGatherBlocks), dim3(256), 0, stream,
                       key, idx, out);
}